// Round 8
// baseline (900.865 us; speedup 1.0000x reference)
//
#include <hip/hip_runtime.h>

constexpr int BN = 512;
constexpr int NITER = 50;

#define CEXP  (-28.853900817779268f)  /* -log2(e)/0.05 */
#define ESH   (14.0f)                 /* E' = 2^(M*CEXP + 14) in fp16 */
#define L2TAU (9.965784284662087f)    /* log2(1000) */

typedef unsigned int u32;

__device__ __forceinline__ float fexp2(float x) { return __builtin_amdgcn_exp2f(x); }
__device__ __forceinline__ float flog2(float x) { return __builtin_amdgcn_logf(x); }

__device__ __forceinline__ float nr_rcp(float x) {
    float r = __builtin_amdgcn_rcpf(x);
    return fmaf(r, fmaf(-x, r, 1.0f), r);
}

template <int CTRL>
__device__ __forceinline__ float dppx(float x) {
    return __int_as_float(__builtin_amdgcn_update_dpp(
        0, __float_as_int(x), CTRL, 0xF, 0xF, true));
}

__device__ __forceinline__ float bfly_sum(float x) {
    x += dppx<0xB1>(x);            // xor1 (quad_perm)
    x += dppx<0x4E>(x);            // xor2 (quad_perm)
    x += dppx<0x141>(x);           // xor4 (half_mirror)
    x += dppx<0x140>(x);           // xor8 (mirror)
    x += __shfl_xor(x, 16, 64);
    x += __shfl_xor(x, 32, 64);
    return x;
}
__device__ __forceinline__ float bfly_max(float x) {
    x = fmaxf(x, dppx<0xB1>(x));
    x = fmaxf(x, dppx<0x4E>(x));
    x = fmaxf(x, dppx<0x141>(x));
    x = fmaxf(x, dppx<0x140>(x));
    x = fmaxf(x, __shfl_xor(x, 16, 64));
    x = fmaxf(x, __shfl_xor(x, 32, 64));
    return x;
}

// accLo += f16lo(e2)*pLo ; accHi += f16hi(e2)*pHi  (one VALU op each)
__device__ __forceinline__ void fma_mix2(float& accLo, float& accHi, u32 e2,
                                         float pLo, float pHi) {
    asm("v_fma_mix_f32 %0, %2, %3, %0 op_sel_hi:[1,0,0]\n\t"
        "v_fma_mix_f32 %1, %2, %4, %1 op_sel:[1,0,0] op_sel_hi:[1,0,0]"
        : "+v"(accLo), "+v"(accHi)
        : "v"(e2), "v"(pLo), "v"(pHi));
}

// async global->LDS: 64 lanes x 16B = 1KB per instruction, lds dst wave-uniform
__device__ __forceinline__ void gload16(const u32* g, void* l) {
    __builtin_amdgcn_global_load_lds(
        (const __attribute__((address_space(1))) u32*)g,
        (__attribute__((address_space(3))) u32*)l, 16, 0, 0);
}

// barrier that drains LDS ops only — keeps global_load_lds prefetch in flight
__device__ __forceinline__ void barrier_lgkm() {
    asm volatile("s_waitcnt lgkmcnt(0)\n\ts_barrier" ::: "memory");
}

// ---------------- Kernel A: E' = fp16(2^(M*CEXP+14)), stored transposed ----------------
__global__ __launch_bounds__(256)
void prep_exp_t(const float* __restrict__ X, float* __restrict__ out)
{
    const int blk  = blockIdx.x;
    const int b    = blk >> 4;
    const int tile = blk & 15;
    const int i0   = (tile >> 2) << 7;
    const int j0   = (tile & 3) << 7;
    const int tid  = threadIdx.x;

    const float* __restrict__ Mb = X + (size_t)b * (BN * BN);
    _Float16* __restrict__ Et = reinterpret_cast<_Float16*>(out + (size_t)b * (BN * BN));

    __shared__ _Float16 T[128][130];

    #pragma unroll
    for (int k = 0; k < 16; ++k) {
        int idx = tid + (k << 8);
        int fi  = idx >> 5;
        int fj  = idx & 31;
        float4 m = *reinterpret_cast<const float4*>(Mb + (size_t)(i0 + fi) * BN + j0 + (fj << 2));
        T[(fj << 2) + 0][fi] = (_Float16)fexp2(fmaf(m.x, CEXP, ESH));
        T[(fj << 2) + 1][fi] = (_Float16)fexp2(fmaf(m.y, CEXP, ESH));
        T[(fj << 2) + 2][fi] = (_Float16)fexp2(fmaf(m.z, CEXP, ESH));
        T[(fj << 2) + 3][fi] = (_Float16)fexp2(fmaf(m.w, CEXP, ESH));
    }
    __syncthreads();
    #pragma unroll
    for (int k = 0; k < 32; ++k) {
        int o  = tid + (k << 8);
        int j  = o >> 6;
        int c2 = o & 63;
        u32 val = *reinterpret_cast<const u32*>(&T[j][c2 << 1]);
        *reinterpret_cast<u32*>(Et + (size_t)(j0 + j) * BN + i0 + (c2 << 1)) = val;
    }
}

// ---------------- Kernel B: async-LDS-streamed iterations ----------------
__global__ __launch_bounds__(1024, 4)
void sinkhorn_iter4(const float* __restrict__ X, float* __restrict__ out,
                    float* __restrict__ cucv)
{
    const int b    = blockIdx.x;
    const int t    = threadIdx.x;
    const int lane = t & 63;
    const int w    = t >> 6;            // 0..15

    const u32* __restrict__ Et4 =
        reinterpret_cast<const u32*>(out + (size_t)b * (BN * BN));

    __shared__ float ah[BN], bh[BN], lu[BN], lv[BN], pv[BN];   // 10 KB
    __shared__ float tpart[8][BN];                             // 16 KB
    __shared__ float wmaxlu[8], wmaxlv[16];
    __shared__ uint4 sbuf[16][2][4][64];                       // 128 KB stream dbuf

    if (t < BN) {
        ah[t] = 0.f; bh[t] = 0.f;
        lu[t] = -9.f; lv[t] = -9.f;
        pv[t] = 0x1p-9f;
    }
    __syncthreads();

    const int jb0 = w << 5;              // 32 columns per wave
    const u32* gb = Et4 + (size_t)jb0 * 256 + (lane << 2);   // per-lane 16B slot

    // prologue: group 0 -> buffer 0
    #pragma unroll
    for (int c = 0; c < 4; ++c)
        gload16(gb + c * 256, &sbuf[w][0][c][0]);

    for (int it = 0; it < NITER; ++it) {
        float pr[8];
        *reinterpret_cast<float4*>(&pr[0]) = *reinterpret_cast<const float4*>(&pv[lane * 8]);
        *reinterpret_cast<float4*>(&pr[4]) = *reinterpret_cast<const float4*>(&pv[lane * 8 + 4]);

        float acc[8] = {0, 0, 0, 0, 0, 0, 0, 0};
        float vml = -1e30f;

        #pragma unroll
        for (int g = 0; g < 8; ++g) {
            const int nb   = (g + 1) & 7;      // g==7 prefetches next iter's group 0
            const int nbuf = (g + 1) & 1;
            #pragma unroll
            for (int c = 0; c < 4; ++c)
                gload16(gb + (size_t)(nb * 4 + c) * 256, &sbuf[w][nbuf][c][0]);

            // previous group's 4 loads retired; only the 4 just-issued in flight
            asm volatile("s_waitcnt vmcnt(4)" ::: "memory");

            const int jb = jb0 + (g << 2);
            uint4 e[4];
            #pragma unroll
            for (int c = 0; c < 4; ++c) e[c] = sbuf[w][g & 1][c][lane];

            const float4 bh4 = *reinterpret_cast<const float4*>(&bh[jb]);
            float q[4];
            #pragma unroll
            for (int c = 0; c < 4; ++c) {
                float s0 = 0.f, s1 = 0.f;
                fma_mix2(s0, s1, e[c].x, pr[0], pr[1]);
                fma_mix2(s0, s1, e[c].y, pr[2], pr[3]);
                fma_mix2(s0, s1, e[c].z, pr[4], pr[5]);
                fma_mix2(s0, s1, e[c].w, pr[6], pr[7]);
                float s = bfly_sum(s0 + s1) * 0x1p-14f;
                q[c] = nr_rcp(s);
                const float bj = (c == 0) ? bh4.x : (c == 1) ? bh4.y : (c == 2) ? bh4.z : bh4.w;
                float lvj = -bj - flog2(s);
                vml = fmaxf(vml, lvj);
                if (lane == 0) lv[jb + c] = lvj;
            }
            #pragma unroll
            for (int c = 0; c < 4; ++c) {
                fma_mix2(acc[0], acc[1], e[c].x, q[c], q[c]);
                fma_mix2(acc[2], acc[3], e[c].y, q[c], q[c]);
                fma_mix2(acc[4], acc[5], e[c].z, q[c], q[c]);
                fma_mix2(acc[6], acc[7], e[c].w, q[c], q[c]);
            }
        }

        // ---- two-phase tpart fold (raw barriers keep prefetch alive) ----
        if (w < 8) {
            *reinterpret_cast<float4*>(&tpart[w][lane * 8]) =
                make_float4(acc[0], acc[1], acc[2], acc[3]);
            *reinterpret_cast<float4*>(&tpart[w][lane * 8 + 4]) =
                make_float4(acc[4], acc[5], acc[6], acc[7]);
        }
        if (lane == 0) wmaxlv[w] = vml;
        barrier_lgkm();
        if (w >= 8) {
            float4* p0 = reinterpret_cast<float4*>(&tpart[w - 8][lane * 8]);
            float4* p1 = reinterpret_cast<float4*>(&tpart[w - 8][lane * 8 + 4]);
            float4 o0 = *p0, o1 = *p1;
            o0.x += acc[0]; o0.y += acc[1]; o0.z += acc[2]; o0.w += acc[3];
            o1.x += acc[4]; o1.y += acc[5]; o1.z += acc[6]; o1.w += acc[7];
            *p0 = o0; *p1 = o1;
        }
        barrier_lgkm();

        float lun = 0.f, tt = 0.f;
        if (t < BN) {
            float p0 = 0, p1 = 0, p2 = 0, p3 = 0;
            #pragma unroll
            for (int w2 = 0; w2 < 8; w2 += 4) {
                p0 += tpart[w2 + 0][t];
                p1 += tpart[w2 + 1][t];
                p2 += tpart[w2 + 2][t];
                p3 += tpart[w2 + 3][t];
            }
            tt  = ((p0 + p1) + (p2 + p3)) * 0x1p-14f;
            lun = -ah[t] - flog2(tt);
            float m = bfly_max(lun);
            if (lane == 0) wmaxlu[w] = m;
        }
        barrier_lgkm();

        if (t < BN) {
            float mlu = wmaxlu[0], mlv = wmaxlv[0];
            #pragma unroll
            for (int i2 = 1; i2 < 8; ++i2)  mlu = fmaxf(mlu, wmaxlu[i2]);
            #pragma unroll
            for (int i2 = 1; i2 < 16; ++i2) mlv = fmaxf(mlv, wmaxlv[i2]);
            if (mlu > L2TAU || mlv > L2TAU) {
                float an = ah[t] + lun;
                ah[t] = an;
                lu[t] = -9.f;
                pv[t] = fexp2(an - 9.0f);
                bh[t] += lv[t];
                lv[t] = -9.f;
            } else {
                lu[t] = lun;
                pv[t] = nr_rcp(tt);
            }
        }
        barrier_lgkm();
    }

    // drain stray prefetch before leaving the streaming region
    asm volatile("s_waitcnt vmcnt(0)" ::: "memory");

    if (cucv != nullptr) {
        if (t < BN) {
            cucv[(size_t)b * 1024 + t]       = ah[t] + lu[t];
            cucv[(size_t)b * 1024 + 512 + t] = bh[t] + lv[t];
        }
    } else {
        // fused fallback epilogue (ws too small)
        if (t < BN) {
            pv[t] = ah[t] + lu[t];
            lv[t] = bh[t] + lv[t];
        }
        __syncthreads();
        const int j  = t & 511;
        const int i0 = (t >> 9) * 256;
        const float cvj = lv[j];
        const float* __restrict__ Mb = X + (size_t)b * (BN * BN);
        float* __restrict__ Gb = out + (size_t)b * (BN * BN);
        #pragma unroll 4
        for (int i = i0; i < i0 + 256; ++i)
            Gb[(size_t)i * BN + j] = fexp2(fmaf(Mb[(size_t)i * BN + j], CEXP, pv[i] + cvj));
    }
}

// ---------------- Kernel C: Gamma epilogue on the full chip ----------------
__global__ __launch_bounds__(256)
void gamma_out(const float* __restrict__ X, float* __restrict__ out,
               const float* __restrict__ cucv)
{
    const int blk  = blockIdx.x;
    const int b    = blk >> 4;
    const int tile = blk & 15;       // 32 rows per tile
    const int tid  = threadIdx.x;
    const int i0   = tile << 5;

    __shared__ float cu[32];
    __shared__ float cv[BN];

    if (tid < 32) cu[tid] = cucv[(size_t)b * 1024 + i0 + tid];
    cv[tid]        = cucv[(size_t)b * 1024 + 512 + tid];
    cv[tid + 256]  = cucv[(size_t)b * 1024 + 768 + tid];
    __syncthreads();

    const float* __restrict__ Mb = X + (size_t)b * (BN * BN);
    float* __restrict__ Gb = out + (size_t)b * (BN * BN);
    const float4* __restrict__ cv4 = reinterpret_cast<const float4*>(cv);

    #pragma unroll
    for (int k = 0; k < 16; ++k) {
        int idx = tid + (k << 8);        // 0..4095 float4s in this 32x512 tile
        int r   = idx >> 7;              // 0..31
        int c4  = idx & 127;             // float4 column index
        int i   = i0 + r;
        float4 m = *reinterpret_cast<const float4*>(Mb + (size_t)i * BN + (c4 << 2));
        float4 c = cv4[c4];
        float cui = cu[r];
        float4 g;
        g.x = fexp2(fmaf(m.x, CEXP, cui + c.x));
        g.y = fexp2(fmaf(m.y, CEXP, cui + c.y));
        g.z = fexp2(fmaf(m.z, CEXP, cui + c.z));
        g.w = fexp2(fmaf(m.w, CEXP, cui + c.w));
        *reinterpret_cast<float4*>(Gb + (size_t)i * BN + (c4 << 2)) = g;
    }
}

extern "C" void kernel_launch(void* const* d_in, const int* in_sizes, int n_in,
                              void* d_out, int out_size, void* d_ws, size_t ws_size,
                              hipStream_t stream)
{
    const float* X = (const float*)d_in[0];
    float* out = (float*)d_out;
    const int batch = in_sizes[0] / (BN * BN);   // 128

    prep_exp_t<<<batch * 16, 256, 0, stream>>>(X, out);

    const size_t cucv_bytes = (size_t)batch * 1024 * sizeof(float);  // 512 KB
    if (ws_size >= cucv_bytes) {
        float* cucv = (float*)d_ws;
        sinkhorn_iter4<<<batch, 1024, 0, stream>>>(X, out, cucv);
        gamma_out<<<batch * 16, 256, 0, stream>>>(X, out, cucv);
    } else {
        sinkhorn_iter4<<<batch, 1024, 0, stream>>>(X, out, nullptr);
    }
}